// Round 1
// baseline (1210.942 us; speedup 1.0000x reference)
//
#include <hip/hip_runtime.h>

#define NUM_B 256
#define SEQ_L 100
#define D0    500
#define D12   250
#define NH1   200
#define NH2   1000
#define KPAD  1024
#define NPIX  240000
#define BN    128
#define BK    64

typedef __attribute__((ext_vector_type(8))) short short8;
typedef __attribute__((ext_vector_type(4))) float f32x4;

static __device__ __forceinline__ unsigned short f2bf(float f) {
  unsigned int u = __builtin_bit_cast(unsigned int, f);
  u += 0x7fffu + ((u >> 16) & 1u);   // round-to-nearest-even
  return (unsigned short)(u >> 16);
}

// ---------------- Kernel 1: embedding-bag means + fc1 + fc2 -> h2 (bf16, K padded to 1024)
__global__ __launch_bounds__(256) void embed_mlp_kernel(
    const int* __restrict__ bucket, const int* __restrict__ ids,
    const float* __restrict__ W100, const float* __restrict__ W10,
    const float* __restrict__ W0,
    const float* __restrict__ fc1_w, const float* __restrict__ fc1_b,
    const float* __restrict__ fc2_w, const float* __restrict__ fc2_b,
    unsigned short* __restrict__ h2out)
{
  __shared__ float xs[1000];
  __shared__ float h1s[NH1];
  const int row = blockIdx.x;
  const int t = threadIdx.x;
  const int* rb = bucket + row * SEQ_L;
  const int* ri = ids + row * SEQ_L;

  // per-thread accumulators: e0[t], e0[t+256], e1[t], e2[t]
  float a00 = 0.f, a01 = 0.f, a1 = 0.f, a2 = 0.f;
  int c0 = 0, c1 = 0, c2 = 0;
  for (int l = 0; l < SEQ_L; ++l) {
    const int b = rb[l];
    const long id = ri[l];
    if (b == 0) {
      ++c0;
      const float* r = W100 + id * D0;
      a00 += r[t];
      if (t < D0 - 256) a01 += r[t + 256];
    } else if (b == 1) {
      ++c1;
      if (t < D12) a1 += W10[id * D12 + t];
    } else {
      ++c2;
      if (t < D12) a2 += W0[id * D12 + t];
    }
  }
  xs[t] = c0 ? a00 / (float)c0 : 0.f;
  if (t < D0 - 256) xs[t + 256] = c0 ? a01 / (float)c0 : 0.f;
  if (t < D12) {
    xs[D0 + t]       = c1 ? a1 / (float)c1 : 0.f;
    xs[D0 + D12 + t] = c2 ? a2 / (float)c2 : 0.f;
  }
  __syncthreads();

  const int wid = t >> 6, lane = t & 63;

  // fc1: h1[o] = relu(sum_k x[k]*fc1_w[o,k] + b), coalesced K-split + wave reduce
  for (int o = wid; o < NH1; o += 4) {
    const float* wr = fc1_w + o * 1000;
    float p = 0.f;
    for (int k = lane; k < 1000; k += 64) p += xs[k] * wr[k];
    #pragma unroll
    for (int off = 32; off; off >>= 1) p += __shfl_down(p, off);
    if (lane == 0) h1s[o] = fmaxf(p + fc1_b[o], 0.f);
  }
  __syncthreads();

  // fc2 -> h2 (bf16)
  unsigned short* hrow = h2out + (long)row * KPAD;
  for (int o = wid; o < NH2; o += 4) {
    const float* wr = fc2_w + o * NH1;
    float p = 0.f;
    for (int k = lane; k < NH1; k += 64) p += h1s[k] * wr[k];
    #pragma unroll
    for (int off = 32; off; off >>= 1) p += __shfl_down(p, off);
    if (lane == 0) hrow[o] = f2bf(fmaxf(p + fc2_b[o], 0.f));
  }
  if (t < KPAD - NH2) hrow[NH2 + t] = 0;  // zero K-padding
}

// ---------------- Kernel 2: ratings = h2 @ out_w^T + out_b
// BM=256 (full M: out_w read exactly once), BN=128, BK=64, 8 waves (2x4).
__global__ __launch_bounds__(512) void out_gemm_kernel(
    const unsigned short* __restrict__ h2,  // [256][1024] bf16 bits
    const float* __restrict__ out_w,        // [240000][1000] fp32
    const float* __restrict__ out_b,        // [240000]
    float* __restrict__ out)                // [256][240000]
{
  __shared__ uint4 ldsbuf[(256 * BK * 2 + BN * BK * 2) / 16];  // 48 KB
  unsigned char* As = (unsigned char*)ldsbuf;         // [256][64] bf16, swizzled
  unsigned char* Bs = As + 256 * BK * 2;              // [128][64] bf16, swizzled

  const int tid = threadIdx.x;
  const long n0 = (long)blockIdx.x * BN;

  uint4 aReg[4];
  f32x4 bReg[4];
  const f32x4 fzero = {0.f, 0.f, 0.f, 0.f};

  auto loadA = [&](int k0) {
    #pragma unroll
    for (int i = 0; i < 4; ++i) {
      int c = tid + 512 * i;
      int rw = c >> 3, k8 = c & 7;            // row, 8-elem k-group
      aReg[i] = *(const uint4*)(h2 + rw * KPAD + k0 + k8 * 8);
    }
  };
  auto loadB = [&](int k0) {
    #pragma unroll
    for (int i = 0; i < 4; ++i) {
      int c = tid + 512 * i;
      int n = c >> 4, kg = c & 15;            // n-row, 4-float k-group
      int k = k0 + kg * 4;
      bReg[i] = (k < 1000) ? *(const f32x4*)(out_w + (n0 + n) * 1000 + k) : fzero;
    }
  };
  auto storeA = [&]() {
    #pragma unroll
    for (int i = 0; i < 4; ++i) {
      int c = tid + 512 * i;
      int rw = c >> 3, k8 = c & 7;
      int off = rw * 128 + ((k8 * 16) ^ ((rw & 7) << 4));
      *(uint4*)(As + off) = aReg[i];
    }
  };
  auto storeB = [&]() {
    #pragma unroll
    for (int i = 0; i < 4; ++i) {
      int c = tid + 512 * i;
      int n = c >> 4, kg = c & 15;
      ushort4 h;
      h.x = f2bf(bReg[i].x); h.y = f2bf(bReg[i].y);
      h.z = f2bf(bReg[i].z); h.w = f2bf(bReg[i].w);
      int off = n * 128 + ((kg * 8) ^ ((n & 7) << 4));
      *(ushort4*)(Bs + off) = h;
    }
  };

  const int wid = tid >> 6, lane = tid & 63;
  const int wm = wid >> 2, wn = wid & 3;      // wave grid 2 (M) x 4 (N)
  const int lrow = lane & 15, lkg = lane >> 4;

  f32x4 acc[8][2];
  #pragma unroll
  for (int m = 0; m < 8; ++m) { acc[m][0] = fzero; acc[m][1] = fzero; }

  loadA(0); loadB(0);
  for (int kt = 0; kt < 16; ++kt) {
    storeA(); storeB();
    __syncthreads();
    if (kt < 15) { loadA((kt + 1) * BK); loadB((kt + 1) * BK); }  // prefetch overlaps MFMA
    #pragma unroll
    for (int kk = 0; kk < 2; ++kk) {
      short8 bf[2];
      #pragma unroll
      for (int n = 0; n < 2; ++n) {
        int nr = wn * 32 + n * 16 + lrow;
        int off = nr * 128 + (((kk * 64) + lkg * 16) ^ ((nr & 7) << 4));
        bf[n] = *(const short8*)(Bs + off);
      }
      #pragma unroll
      for (int m = 0; m < 8; ++m) {
        int rr = wm * 128 + m * 16 + lrow;
        int off = rr * 128 + (((kk * 64) + lkg * 16) ^ ((rr & 7) << 4));
        short8 af = *(const short8*)(As + off);
        acc[m][0] = __builtin_amdgcn_mfma_f32_16x16x32_bf16(af, bf[0], acc[m][0], 0, 0, 0);
        acc[m][1] = __builtin_amdgcn_mfma_f32_16x16x32_bf16(af, bf[1], acc[m][1], 0, 0, 0);
      }
    }
    __syncthreads();
  }

  // epilogue: C/D layout col=lane&15, row=(lane>>4)*4+reg
  #pragma unroll
  for (int n = 0; n < 2; ++n) {
    const long col = n0 + wn * 32 + n * 16 + lrow;
    const float bias = out_b[col];
    #pragma unroll
    for (int m = 0; m < 8; ++m) {
      const int rbase = wm * 128 + m * 16 + lkg * 4;
      const f32x4 a = acc[m][n];
      #pragma unroll
      for (int r = 0; r < 4; ++r)
        out[(long)(rbase + r) * NPIX + col] = a[r] + bias;
    }
  }
}

extern "C" void kernel_launch(void* const* d_in, const int* in_sizes, int n_in,
                              void* d_out, int out_size, void* d_ws, size_t ws_size,
                              hipStream_t stream) {
  const int*   bucket = (const int*)d_in[0];
  const int*   ids    = (const int*)d_in[1];
  const float* W100   = (const float*)d_in[2];
  const float* W10    = (const float*)d_in[3];
  const float* W0     = (const float*)d_in[4];
  const float* fc1w   = (const float*)d_in[5];
  const float* fc1b   = (const float*)d_in[6];
  const float* fc2w   = (const float*)d_in[7];
  const float* fc2b   = (const float*)d_in[8];
  const float* outw   = (const float*)d_in[9];
  const float* outb   = (const float*)d_in[10];
  float* out = (float*)d_out;
  unsigned short* h2w = (unsigned short*)d_ws;  // 256*1024*2B = 512 KB

  embed_mlp_kernel<<<NUM_B, 256, 0, stream>>>(bucket, ids, W100, W10, W0,
                                              fc1w, fc1b, fc2w, fc2b, h2w);
  out_gemm_kernel<<<NPIX / BN, 512, 0, stream>>>(h2w, outw, outb, out);
}

// Round 2
// 578.518 us; speedup vs baseline: 2.0932x; 2.0932x over previous
//
#include <hip/hip_runtime.h>

#define NUM_B 256
#define SEQ_L 100
#define NPIX  240000
#define KPAD  1024
#define BN    128
#define BK    64

typedef __attribute__((ext_vector_type(8))) short short8;
typedef __attribute__((ext_vector_type(4))) float f32x4;

static __device__ __forceinline__ unsigned short f2bf(float f) {
  unsigned int u = __builtin_bit_cast(unsigned int, f);
  u += 0x7fffu + ((u >> 16) & 1u);   // round-to-nearest-even
  return (unsigned short)(u >> 16);
}

// ---------------- Kernel 1 (fused): embedding-bag means + fc1 + fc2 -> h2 bf16 [256][1024]
// One block per batch row, 512 threads (8 waves). Waves split tokens with
// register accumulators (8-deep load ILP); LDS tree-reduce; 16-lane-group
// dot products for fc1/fc2 (32 outputs in flight).
__global__ __launch_bounds__(512) void embed_mlp_kernel(
    const int* __restrict__ bucket, const int* __restrict__ ids,
    const float* __restrict__ W100, const float* __restrict__ W10,
    const float* __restrict__ W0,
    const float* __restrict__ fc1_w, const float* __restrict__ fc1_b,
    const float* __restrict__ fc2_w, const float* __restrict__ fc2_b,
    unsigned short* __restrict__ h2out)
{
  __shared__ __align__(16) float xw[8][1000];   // per-wave partial sums (32 KB)
  __shared__ __align__(16) float xs[1000];
  __shared__ __align__(16) float h1s[200];
  __shared__ int sb[SEQ_L], sid[SEQ_L];
  __shared__ int cnt[8][3];
  __shared__ int cntT[3];

  const int row = blockIdx.x, tid = threadIdx.x;
  const int wid = tid >> 6, lane = tid & 63;

  if (tid < SEQ_L) {
    sb[tid]  = bucket[row * SEQ_L + tid];
    sid[tid] = ids[row * SEQ_L + tid];
  }
  __syncthreads();

  float acc0[8] = {0,0,0,0,0,0,0,0};
  float acc1[4] = {0,0,0,0};
  float acc2[4] = {0,0,0,0};
  int c0 = 0, c1 = 0, c2 = 0;

  for (int l = wid; l < SEQ_L; l += 8) {       // wave-uniform token, uniform branch
    const int b = sb[l];
    const long id = sid[l];
    if (b == 0) {
      ++c0; const float* r = W100 + id * 500;
      #pragma unroll
      for (int j = 0; j < 7; ++j) acc0[j] += r[lane + 64 * j];
      if (lane < 52) acc0[7] += r[lane + 448];
    } else if (b == 1) {
      ++c1; const float* r = W10 + id * 250;
      #pragma unroll
      for (int j = 0; j < 3; ++j) acc1[j] += r[lane + 64 * j];
      if (lane < 58) acc1[3] += r[lane + 192];
    } else {
      ++c2; const float* r = W0 + id * 250;
      #pragma unroll
      for (int j = 0; j < 3; ++j) acc2[j] += r[lane + 64 * j];
      if (lane < 58) acc2[3] += r[lane + 192];
    }
  }
  {
    float* xp = xw[wid];
    #pragma unroll
    for (int j = 0; j < 8; ++j) { int d = lane + 64 * j; if (d < 500) xp[d] = acc0[j]; }
    #pragma unroll
    for (int j = 0; j < 4; ++j) { int d = lane + 64 * j; if (d < 250) xp[500 + d] = acc1[j]; }
    #pragma unroll
    for (int j = 0; j < 4; ++j) { int d = lane + 64 * j; if (d < 250) xp[750 + d] = acc2[j]; }
    if (lane == 0) { cnt[wid][0] = c0; cnt[wid][1] = c1; cnt[wid][2] = c2; }
  }
  __syncthreads();
  if (tid < 3) { int s = 0; for (int w = 0; w < 8; ++w) s += cnt[w][tid]; cntT[tid] = s; }
  __syncthreads();
  for (int d = tid; d < 1000; d += 512) {
    float s = 0.f;
    #pragma unroll
    for (int w = 0; w < 8; ++w) s += xw[w][d];
    const int bkt = d < 500 ? 0 : (d < 750 ? 1 : 2);
    const int c = cntT[bkt];
    xs[d] = c ? s / (float)c : 0.f;
  }
  __syncthreads();

  const int g = tid >> 4, sl = tid & 15;       // 32 sixteen-lane groups

  // fc1: h1[o] = relu(x . fc1_w[o] + b)
  for (int o = g; o < 200; o += 32) {
    const f32x4* wr = (const f32x4*)(fc1_w + o * 1000);
    const f32x4* xv = (const f32x4*)xs;
    float p = 0.f;
    for (int j = sl; j < 250; j += 16) {
      f32x4 a = xv[j], b = wr[j];
      p += a.x * b.x + a.y * b.y + a.z * b.z + a.w * b.w;
    }
    #pragma unroll
    for (int off = 8; off; off >>= 1) p += __shfl_down(p, off, 16);
    if (sl == 0) h1s[o] = fmaxf(p + fc1_b[o], 0.f);
  }
  __syncthreads();

  // fc2 -> h2 bf16
  unsigned short* hrow = h2out + (long)row * KPAD;
  for (int o = g; o < 1000; o += 32) {
    const f32x4* wr = (const f32x4*)(fc2_w + o * 200);
    const f32x4* hv = (const f32x4*)h1s;
    float p = 0.f;
    #pragma unroll
    for (int j = sl; j < 50; j += 16) {
      f32x4 a = hv[j], b = wr[j];
      p += a.x * b.x + a.y * b.y + a.z * b.z + a.w * b.w;
    }
    #pragma unroll
    for (int off = 8; off; off >>= 1) p += __shfl_down(p, off, 16);
    if (sl == 0) hrow[o] = f2bf(fmaxf(p + fc2_b[o], 0.f));
  }
  if (tid < KPAD - 1000) hrow[1000 + tid] = 0;
}

// ---------------- Kernel 2: ratings = h2 @ out_w^T + out_b
// BM=256 (full M: out_w read exactly once), BN=128, BK=64, 8 waves (2x4).
__global__ __launch_bounds__(512) void out_gemm_kernel(
    const unsigned short* __restrict__ h2,  // [256][1024] bf16 bits
    const float* __restrict__ out_w,        // [240000][1000] fp32
    const float* __restrict__ out_b,        // [240000]
    float* __restrict__ out)                // [256][240000]
{
  __shared__ uint4 ldsbuf[(256 * BK * 2 + BN * BK * 2) / 16];  // 48 KB
  unsigned char* As = (unsigned char*)ldsbuf;         // [256][64] bf16, swizzled
  unsigned char* Bs = As + 256 * BK * 2;              // [128][64] bf16, swizzled

  const int tid = threadIdx.x;

  // bijective XCD swizzle (nwg=1875, q=234, r=3) — m204 variant
  const int q = 1875 / 8, r = 1875 % 8;
  const int xcd = blockIdx.x & 7, bidx = blockIdx.x >> 3;
  const int wg = (xcd < r ? xcd * (q + 1) : r * (q + 1) + (xcd - r) * q) + bidx;
  const long n0 = (long)wg * BN;

  uint4 aReg[4];
  f32x4 bReg[4];
  const f32x4 fzero = {0.f, 0.f, 0.f, 0.f};

  auto loadA = [&](int k0) {
    #pragma unroll
    for (int i = 0; i < 4; ++i) {
      int c = tid + 512 * i;
      int rw = c >> 3, k8 = c & 7;            // row, 8-elem k-group
      aReg[i] = *(const uint4*)(h2 + rw * KPAD + k0 + k8 * 8);
    }
  };
  auto loadB = [&](int k0) {
    #pragma unroll
    for (int i = 0; i < 4; ++i) {
      int c = tid + 512 * i;
      int n = c >> 4, kg = c & 15;            // n-row, 4-float k-group
      int k = k0 + kg * 4;
      bReg[i] = (k < 1000)
        ? __builtin_nontemporal_load((const f32x4*)(out_w + (n0 + n) * 1000 + k))
        : fzero;
    }
  };
  auto storeA = [&]() {
    #pragma unroll
    for (int i = 0; i < 4; ++i) {
      int c = tid + 512 * i;
      int rw = c >> 3, k8 = c & 7;
      int off = rw * 128 + ((k8 * 16) ^ ((rw & 7) << 4));
      *(uint4*)(As + off) = aReg[i];
    }
  };
  auto storeB = [&]() {
    #pragma unroll
    for (int i = 0; i < 4; ++i) {
      int c = tid + 512 * i;
      int n = c >> 4, kg = c & 15;
      ushort4 h;
      h.x = f2bf(bReg[i].x); h.y = f2bf(bReg[i].y);
      h.z = f2bf(bReg[i].z); h.w = f2bf(bReg[i].w);
      int off = n * 128 + ((kg * 8) ^ ((n & 7) << 4));
      *(ushort4*)(Bs + off) = h;
    }
  };

  const int wid = tid >> 6, lane = tid & 63;
  const int wm = wid >> 2, wn = wid & 3;      // wave grid 2 (M) x 4 (N)
  const int lrow = lane & 15, lkg = lane >> 4;

  f32x4 acc[8][2];
  #pragma unroll
  for (int m = 0; m < 8; ++m) { acc[m][0] = fzero; acc[m][1] = fzero; }

  loadA(0); loadB(0);
  for (int kt = 0; kt < 16; ++kt) {
    storeA(); storeB();
    __syncthreads();
    if (kt < 15) { loadA((kt + 1) * BK); loadB((kt + 1) * BK); }  // prefetch overlaps MFMA
    #pragma unroll
    for (int kk = 0; kk < 2; ++kk) {
      short8 bf[2];
      #pragma unroll
      for (int n = 0; n < 2; ++n) {
        int nr = wn * 32 + n * 16 + lrow;
        int off = nr * 128 + (((kk * 64) + lkg * 16) ^ ((nr & 7) << 4));
        bf[n] = *(const short8*)(Bs + off);
      }
      #pragma unroll
      for (int m = 0; m < 8; ++m) {
        int rr = wm * 128 + m * 16 + lrow;
        int off = rr * 128 + (((kk * 64) + lkg * 16) ^ ((rr & 7) << 4));
        short8 af = *(const short8*)(As + off);
        acc[m][0] = __builtin_amdgcn_mfma_f32_16x16x32_bf16(af, bf[0], acc[m][0], 0, 0, 0);
        acc[m][1] = __builtin_amdgcn_mfma_f32_16x16x32_bf16(af, bf[1], acc[m][1], 0, 0, 0);
      }
    }
    __syncthreads();
  }

  // epilogue: C/D layout col=lane&15, row=(lane>>4)*4+reg
  #pragma unroll
  for (int n = 0; n < 2; ++n) {
    const long col = n0 + wn * 32 + n * 16 + lrow;
    const float bias = out_b[col];
    #pragma unroll
    for (int m = 0; m < 8; ++m) {
      const int rbase = wm * 128 + m * 16 + lkg * 4;
      const f32x4 a = acc[m][n];
      #pragma unroll
      for (int rr = 0; rr < 4; ++rr)
        __builtin_nontemporal_store(a[rr] + bias, &out[(long)(rbase + rr) * NPIX + col]);
    }
  }
}

extern "C" void kernel_launch(void* const* d_in, const int* in_sizes, int n_in,
                              void* d_out, int out_size, void* d_ws, size_t ws_size,
                              hipStream_t stream) {
  const int*   bucket = (const int*)d_in[0];
  const int*   ids    = (const int*)d_in[1];
  const float* W100   = (const float*)d_in[2];
  const float* W10    = (const float*)d_in[3];
  const float* W0     = (const float*)d_in[4];
  const float* fc1w   = (const float*)d_in[5];
  const float* fc1b   = (const float*)d_in[6];
  const float* fc2w   = (const float*)d_in[7];
  const float* fc2b   = (const float*)d_in[8];
  const float* outw   = (const float*)d_in[9];
  const float* outb   = (const float*)d_in[10];
  float* out = (float*)d_out;
  unsigned short* h2w = (unsigned short*)d_ws;  // 256*1024*2B = 512 KB

  embed_mlp_kernel<<<NUM_B, 512, 0, stream>>>(bucket, ids, W100, W10, W0,
                                              fc1w, fc1b, fc2w, fc2b, h2w);
  out_gemm_kernel<<<NPIX / BN, 512, 0, stream>>>(h2w, outw, outb, out);
}

// Round 3
// 443.795 us; speedup vs baseline: 2.7286x; 1.3036x over previous
//
#include <hip/hip_runtime.h>

#define NUM_B 256
#define SEQ_L 100
#define NPIX  240000
#define KPAD  1024
#define BN    128
#define BK    128
#define NWG   1875   // NPIX / BN

typedef __attribute__((ext_vector_type(8))) short short8;
typedef __attribute__((ext_vector_type(4))) float f32x4;

static __device__ __forceinline__ unsigned short f2bf(float f) {
  unsigned int u = __builtin_bit_cast(unsigned int, f);
  u += 0x7fffu + ((u >> 16) & 1u);   // round-to-nearest-even
  return (unsigned short)(u >> 16);
}

// ---------------- Kernel 1 (fused): embedding-bag means + fc1 + fc2 -> h2 bf16 [256][1024]
__global__ __launch_bounds__(512) void embed_mlp_kernel(
    const int* __restrict__ bucket, const int* __restrict__ ids,
    const float* __restrict__ W100, const float* __restrict__ W10,
    const float* __restrict__ W0,
    const float* __restrict__ fc1_w, const float* __restrict__ fc1_b,
    const float* __restrict__ fc2_w, const float* __restrict__ fc2_b,
    unsigned short* __restrict__ h2out)
{
  __shared__ __align__(16) float xw[8][1000];   // per-wave partial sums (32 KB)
  __shared__ __align__(16) float xs[1000];
  __shared__ __align__(16) float h1s[200];
  __shared__ int sb[SEQ_L], sid[SEQ_L];
  __shared__ int cnt[8][3];
  __shared__ int cntT[3];

  const int row = blockIdx.x, tid = threadIdx.x;
  const int wid = tid >> 6, lane = tid & 63;

  if (tid < SEQ_L) {
    sb[tid]  = bucket[row * SEQ_L + tid];
    sid[tid] = ids[row * SEQ_L + tid];
  }
  __syncthreads();

  float acc0[8] = {0,0,0,0,0,0,0,0};
  float acc1[4] = {0,0,0,0};
  float acc2[4] = {0,0,0,0};
  int c0 = 0, c1 = 0, c2 = 0;

  for (int l = wid; l < SEQ_L; l += 8) {       // wave-uniform token, uniform branch
    const int b = sb[l];
    const long id = sid[l];
    if (b == 0) {
      ++c0; const float* r = W100 + id * 500;
      #pragma unroll
      for (int j = 0; j < 7; ++j) acc0[j] += r[lane + 64 * j];
      if (lane < 52) acc0[7] += r[lane + 448];
    } else if (b == 1) {
      ++c1; const float* r = W10 + id * 250;
      #pragma unroll
      for (int j = 0; j < 3; ++j) acc1[j] += r[lane + 64 * j];
      if (lane < 58) acc1[3] += r[lane + 192];
    } else {
      ++c2; const float* r = W0 + id * 250;
      #pragma unroll
      for (int j = 0; j < 3; ++j) acc2[j] += r[lane + 64 * j];
      if (lane < 58) acc2[3] += r[lane + 192];
    }
  }
  {
    float* xp = xw[wid];
    #pragma unroll
    for (int j = 0; j < 8; ++j) { int d = lane + 64 * j; if (d < 500) xp[d] = acc0[j]; }
    #pragma unroll
    for (int j = 0; j < 4; ++j) { int d = lane + 64 * j; if (d < 250) xp[500 + d] = acc1[j]; }
    #pragma unroll
    for (int j = 0; j < 4; ++j) { int d = lane + 64 * j; if (d < 250) xp[750 + d] = acc2[j]; }
    if (lane == 0) { cnt[wid][0] = c0; cnt[wid][1] = c1; cnt[wid][2] = c2; }
  }
  __syncthreads();
  if (tid < 3) { int s = 0; for (int w = 0; w < 8; ++w) s += cnt[w][tid]; cntT[tid] = s; }
  __syncthreads();
  for (int d = tid; d < 1000; d += 512) {
    float s = 0.f;
    #pragma unroll
    for (int w = 0; w < 8; ++w) s += xw[w][d];
    const int bkt = d < 500 ? 0 : (d < 750 ? 1 : 2);
    const int c = cntT[bkt];
    xs[d] = c ? s / (float)c : 0.f;
  }
  __syncthreads();

  const int g = tid >> 4, sl = tid & 15;       // 32 sixteen-lane groups

  for (int o = g; o < 200; o += 32) {
    const f32x4* wr = (const f32x4*)(fc1_w + o * 1000);
    const f32x4* xv = (const f32x4*)xs;
    float p = 0.f;
    for (int j = sl; j < 250; j += 16) {
      f32x4 a = xv[j], b = wr[j];
      p += a.x * b.x + a.y * b.y + a.z * b.z + a.w * b.w;
    }
    #pragma unroll
    for (int off = 8; off; off >>= 1) p += __shfl_down(p, off, 16);
    if (sl == 0) h1s[o] = fmaxf(p + fc1_b[o], 0.f);
  }
  __syncthreads();

  unsigned short* hrow = h2out + (long)row * KPAD;
  for (int o = g; o < 1000; o += 32) {
    const f32x4* wr = (const f32x4*)(fc2_w + o * 200);
    const f32x4* hv = (const f32x4*)h1s;
    float p = 0.f;
    #pragma unroll
    for (int j = sl; j < 50; j += 16) {
      f32x4 a = hv[j], b = wr[j];
      p += a.x * b.x + a.y * b.y + a.z * b.z + a.w * b.w;
    }
    #pragma unroll
    for (int off = 8; off; off >>= 1) p += __shfl_down(p, off, 16);
    if (sl == 0) hrow[o] = f2bf(fmaxf(p + fc2_b[o], 0.f));
  }
  if (tid < KPAD - 1000) hrow[1000 + tid] = 0;
}

// ---------------- Kernel 2: ratings = h2 @ out_w^T + out_b
// BM=256 (full M: out_w read exactly once), BN=128, BK=128, 8 waves (2x4).
// 512B-contiguous B reads per row per k-tile; LDS-transposed epilogue for
// 512B-contiguous NT output stores.
__global__ __launch_bounds__(512) void out_gemm_kernel(
    const unsigned short* __restrict__ h2,  // [256][1024] bf16 bits
    const float* __restrict__ out_w,        // [240000][1000] fp32
    const float* __restrict__ out_b,        // [240000]
    float* __restrict__ out)                // [256][240000]
{
  __shared__ __align__(16) unsigned char lds[98304];   // 96 KB
  unsigned char* As = lds;             // [256 rows][256B] bf16, XOR-swizzled
  unsigned char* Bs = lds + 65536;     // [128 rows][256B] bf16, XOR-swizzled

  const int tid = threadIdx.x;

  // bijective XCD swizzle (nwg=1875, q=234, r=3)
  const int q = NWG / 8, r = NWG % 8;
  const int xcd = blockIdx.x & 7, bidx = blockIdx.x >> 3;
  const int wg = (xcd < r ? xcd * (q + 1) : r * (q + 1) + (xcd - r) * q) + bidx;
  const long n0 = (long)wg * BN;

  uint4 aReg[8];
  f32x4 bReg[8];
  const f32x4 fz = {0.f, 0.f, 0.f, 0.f};

  // A: 256 rows x 128 k bf16 = 64KB/kt. 16 lanes read 256B contiguous per row.
  auto loadA = [&](int k0) {
    #pragma unroll
    for (int i = 0; i < 8; ++i) {
      int c = tid + 512 * i;
      int rw = c >> 4, k16 = c & 15;
      aReg[i] = *(const uint4*)(h2 + rw * KPAD + k0 + k16 * 8);
    }
  };
  // B: 128 rows x 128 k fp32 = 64KB/kt. 32 lanes read 512B contiguous per row.
  auto loadB = [&](int k0) {
    #pragma unroll
    for (int i = 0; i < 8; ++i) {
      int c = tid + 512 * i;
      int n = c >> 5, qq = c & 31;
      int k = k0 + qq * 4;
      bReg[i] = (k < 1000)
        ? __builtin_nontemporal_load((const f32x4*)(out_w + (n0 + n) * 1000 + k))
        : fz;
    }
  };
  auto storeA = [&]() {
    #pragma unroll
    for (int i = 0; i < 8; ++i) {
      int c = tid + 512 * i;
      int rw = c >> 4, k16 = c & 15;
      *(uint4*)(As + rw * 256 + ((k16 * 16) ^ ((rw & 7) << 4))) = aReg[i];
    }
  };
  auto storeB = [&]() {
    #pragma unroll
    for (int i = 0; i < 8; ++i) {
      int c = tid + 512 * i;
      int n = c >> 5, qq = c & 31;
      ushort4 h;
      h.x = f2bf(bReg[i].x); h.y = f2bf(bReg[i].y);
      h.z = f2bf(bReg[i].z); h.w = f2bf(bReg[i].w);
      *(ushort4*)(Bs + n * 256 + ((qq * 8) ^ ((n & 7) << 4))) = h;
    }
  };

  const int wid = tid >> 6, lane = tid & 63;
  const int wm = wid >> 2, wn = wid & 3;      // wave grid 2 (M) x 4 (N)
  const int lrow = lane & 15, lkg = lane >> 4;

  f32x4 acc[8][2];
  #pragma unroll
  for (int m = 0; m < 8; ++m) { acc[m][0] = fz; acc[m][1] = fz; }

  loadA(0); loadB(0);
  for (int kt = 0; kt < 8; ++kt) {
    storeA(); storeB();
    __syncthreads();
    if (kt < 7) { loadA((kt + 1) * BK); loadB((kt + 1) * BK); }  // prefetch under MFMA
    #pragma unroll
    for (int kk = 0; kk < 4; ++kk) {
      short8 bf[2];
      #pragma unroll
      for (int n = 0; n < 2; ++n) {
        int nr = wn * 32 + n * 16 + lrow;
        bf[n] = *(const short8*)(Bs + nr * 256 + (((kk * 64) + lkg * 16) ^ ((nr & 7) << 4)));
      }
      #pragma unroll
      for (int m = 0; m < 8; ++m) {
        int rr = wm * 128 + m * 16 + lrow;
        short8 af = *(const short8*)(As + rr * 256 + (((kk * 64) + lkg * 16) ^ ((rr & 7) << 4)));
        acc[m][0] = __builtin_amdgcn_mfma_f32_16x16x32_bf16(af, bf[0], acc[m][0], 0, 0, 0);
        acc[m][1] = __builtin_amdgcn_mfma_f32_16x16x32_bf16(af, bf[1], acc[m][1], 0, 0, 0);
      }
    }
    __syncthreads();
  }

  // epilogue: stage 128x128 f32 chunks in LDS, then 512B-contiguous NT stores.
  const float b0 = out_b[n0 + wn * 32 + lrow];
  const float b1 = out_b[n0 + wn * 32 + 16 + lrow];
  float* E = (float*)lds;            // [128][132] floats = 67,584 B (stride 16B-aligned)
  #pragma unroll
  for (int half = 0; half < 2; ++half) {
    __syncthreads();                 // protect LDS reuse across halves
    if (wm == half) {
      #pragma unroll
      for (int m = 0; m < 8; ++m) {
        #pragma unroll
        for (int n = 0; n < 2; ++n) {
          const int col = wn * 32 + n * 16 + lrow;
          const float bias = n ? b1 : b0;
          #pragma unroll
          for (int rr = 0; rr < 4; ++rr) {
            const int rowl = m * 16 + lkg * 4 + rr;
            E[rowl * 132 + col] = acc[m][n][rr] + bias;
          }
        }
      }
    }
    __syncthreads();
    const int rbase = half * 128;
    #pragma unroll
    for (int s = 0; s < 8; ++s) {
      const int rowl = s * 16 + (tid >> 5);
      const int c = (tid & 31) * 4;
      f32x4 v = *(const f32x4*)(E + rowl * 132 + c);
      __builtin_nontemporal_store(v, (f32x4*)(out + (long)(rbase + rowl) * NPIX + n0 + c));
    }
  }
}

extern "C" void kernel_launch(void* const* d_in, const int* in_sizes, int n_in,
                              void* d_out, int out_size, void* d_ws, size_t ws_size,
                              hipStream_t stream) {
  const int*   bucket = (const int*)d_in[0];
  const int*   ids    = (const int*)d_in[1];
  const float* W100   = (const float*)d_in[2];
  const float* W10    = (const float*)d_in[3];
  const float* W0     = (const float*)d_in[4];
  const float* fc1w   = (const float*)d_in[5];
  const float* fc1b   = (const float*)d_in[6];
  const float* fc2w   = (const float*)d_in[7];
  const float* fc2b   = (const float*)d_in[8];
  const float* outw   = (const float*)d_in[9];
  const float* outb   = (const float*)d_in[10];
  float* out = (float*)d_out;
  unsigned short* h2w = (unsigned short*)d_ws;  // 256*1024*2B = 512 KB

  embed_mlp_kernel<<<NUM_B, 512, 0, stream>>>(bucket, ids, W100, W10, W0,
                                              fc1w, fc1b, fc2w, fc2b, h2w);
  out_gemm_kernel<<<NWG, 512, 0, stream>>>(h2w, outw, outb, out);
}